// Round 1
// baseline (142.649 us; speedup 1.0000x reference)
//
#include <hip/hip_runtime.h>
#include <hip/hip_bf16.h>
#include <cstdint>

#define GLOBAL_AS __attribute__((address_space(1)))
#define LDS_AS    __attribute__((address_space(3)))

typedef short s8v  __attribute__((ext_vector_type(8)));
typedef float f4v  __attribute__((ext_vector_type(4)));

#define NEGV (-1e7f)

__device__ __forceinline__ void gload_lds16(const void* g, void* l) {
  __builtin_amdgcn_global_load_lds((const GLOBAL_AS uint32_t*)g,
                                   (LDS_AS uint32_t*)l, 16, 0, 0);
}

__device__ __forceinline__ unsigned short f2bf(float f) {
  union { float f; uint32_t u; } v; v.f = f;
  uint32_t u = v.u;
  u += 0x7fffu + ((u >> 16) & 1u);
  return (unsigned short)(u >> 16);
}

// ---------------- convert bert_out (f32) -> bf16, same layout ----------------
__global__ __launch_bounds__(256) void cvt_a(const float* __restrict__ x,
                                             unsigned short* __restrict__ y,
                                             int n4) {
  int i = blockIdx.x * blockDim.x + threadIdx.x;
  int stride = gridDim.x * blockDim.x;
  for (; i < n4; i += stride) {
    float4 v = ((const float4*)x)[i];
    ushort4 o;
    o.x = f2bf(v.x); o.y = f2bf(v.y); o.z = f2bf(v.z); o.w = f2bf(v.w);
    ((ushort4*)y)[i] = o;
  }
}

// ------------- convert + transpose W1 (K x N f32) -> W1T (N x K bf16) -------------
__global__ __launch_bounds__(256) void cvt_w1t(const float* __restrict__ w1,
                                               unsigned short* __restrict__ w1t) {
  __shared__ float tile[32][33];
  int bx = blockIdx.x & 31;   // n-tile
  int by = blockIdx.x >> 5;   // k-tile
  int tx = threadIdx.x & 31;
  int ty = threadIdx.x >> 5;  // 0..7
#pragma unroll
  for (int j = 0; j < 4; ++j) {
    int kk = ty + j * 8;
    tile[kk][tx] = w1[(size_t)(by * 32 + kk) * 1024 + bx * 32 + tx];
  }
  __syncthreads();
#pragma unroll
  for (int j = 0; j < 4; ++j) {
    int nn = ty + j * 8;
    w1t[(size_t)(bx * 32 + nn) * 1024 + by * 32 + tx] = f2bf(tile[tx][nn]);
  }
}

// ---------------- fused GEMM: h = relu(A*W1 + b1); logits += h * W2 ----------------
// A: [16384][1024] bf16 row-major.  B = W1T: [1024][1024] bf16 (row n = column of W1).
// 128x128 tile, BK=64, 4 waves (2x2 of 64x64), mfma_f32_16x16x32_bf16.
// LDS tiles XOR-swizzled: byte ^= (row&7)<<4 (inverse-swizzled global source,
// linear global_load_lds dest, swizzled ds_read_b128).
__global__ __launch_bounds__(256) void gemm_fused(
    const unsigned short* __restrict__ Abf,
    const unsigned short* __restrict__ Bbf,
    const float* __restrict__ b1,
    const float* __restrict__ W2,     // [1024][3] f32
    float* __restrict__ logits)       // [16384][3] f32, pre-zeroed
{
  __shared__ __align__(16) char lds[32768];
  char* As = lds;            // [128][64] bf16 = 16 KB
  char* Bs = lds + 16384;    // [128][64] bf16 = 16 KB

  // bijective XCD swizzle: 1024 wgs, 8 XCDs, 128 per XCD
  int bid = blockIdx.x;
  int wid = (bid & 7) * 128 + (bid >> 3);
  int mt = wid >> 3;   // 0..127
  int nt = wid & 7;    // 0..7

  int tid  = threadIdx.x;
  int lane = tid & 63;
  int wv   = tid >> 6;
  int wr   = wv >> 1;  // wave row (0..1)
  int wc   = wv & 1;   // wave col (0..1)

  // per-lane epilogue constants (column-indexed)
  float b1v[4];
  float w2v[4][3];
#pragma unroll
  for (int n = 0; n < 4; ++n) {
    int gc = nt * 128 + wc * 64 + n * 16 + (lane & 15);
    b1v[n] = b1[gc];
    w2v[n][0] = W2[gc * 3 + 0];
    w2v[n][1] = W2[gc * 3 + 1];
    w2v[n][2] = W2[gc * 3 + 2];
  }

  f4v acc[4][4];
#pragma unroll
  for (int m = 0; m < 4; ++m)
#pragma unroll
    for (int n = 0; n < 4; ++n)
      acc[m][n] = f4v{0.f, 0.f, 0.f, 0.f};

  const size_t arow0 = (size_t)mt * 128;
  const size_t brow0 = (size_t)nt * 128;

  // staging geometry (per wave: 4 chunks of 1 KB each for A and B)
  int srow_base = (wv * 4) * 8;
  int slane_row = lane >> 3;        // 0..7 within chunk
  int scb       = (lane & 7) * 16;  // byte col 0..112

  for (int k0 = 0; k0 < 1024; k0 += 64) {
#pragma unroll
    for (int c = 0; c < 4; ++c) {
      int chunk = wv * 4 + c;
      int row = srow_base + c * 8 + slane_row;       // 0..127
      int src = scb ^ ((row & 7) << 4);              // inverse-swizzled source col
      gload_lds16(Abf + (arow0 + row) * 1024 + k0 + (src >> 1), As + chunk * 1024);
      gload_lds16(Bbf + (brow0 + row) * 1024 + k0 + (src >> 1), Bs + chunk * 1024);
    }
    __syncthreads();   // drains vmcnt, data visible

#pragma unroll
    for (int kh = 0; kh < 2; ++kh) {
      int kbyte = kh * 64 + ((lane >> 4) << 4);
      s8v av[4], bv[4];
#pragma unroll
      for (int m = 0; m < 4; ++m) {
        int ra = wr * 64 + m * 16 + (lane & 15);
        av[m] = *(const s8v*)(As + ra * 128 + (kbyte ^ ((ra & 7) << 4)));
        int rb = wc * 64 + m * 16 + (lane & 15);
        bv[m] = *(const s8v*)(Bs + rb * 128 + (kbyte ^ ((rb & 7) << 4)));
      }
#pragma unroll
      for (int m = 0; m < 4; ++m)
#pragma unroll
        for (int n = 0; n < 4; ++n)
          acc[m][n] = __builtin_amdgcn_mfma_f32_16x16x32_bf16(av[m], bv[n], acc[m][n], 0, 0, 0);
    }
    __syncthreads();   // all waves done reading before next-stage overwrite
  }

  // epilogue: h = relu(acc + b1), partial logits = h * W2, reduce over 16 lanes, atomicAdd
#pragma unroll
  for (int m = 0; m < 4; ++m) {
#pragma unroll
    for (int q = 0; q < 4; ++q) {
      float p0 = 0.f, p1 = 0.f, p2 = 0.f;
#pragma unroll
      for (int n = 0; n < 4; ++n) {
        float h = acc[m][n][q] + b1v[n];
        h = fmaxf(h, 0.f);
        p0 += h * w2v[n][0];
        p1 += h * w2v[n][1];
        p2 += h * w2v[n][2];
      }
#pragma unroll
      for (int s = 1; s < 16; s <<= 1) {
        p0 += __shfl_xor(p0, s, 64);
        p1 += __shfl_xor(p1, s, 64);
        p2 += __shfl_xor(p2, s, 64);
      }
      if ((lane & 15) == 0) {
        int grow = mt * 128 + wr * 64 + m * 16 + (lane >> 4) * 4 + q;
        atomicAdd(&logits[grow * 3 + 0], p0);
        atomicAdd(&logits[grow * 3 + 1], p1);
        atomicAdd(&logits[grow * 3 + 2], p2);
      }
    }
  }
}

// ---------------- finalize: log-softmax, gather, logsumexp ----------------
__device__ __forceinline__ float blockReduceSum(float v, float* red, int t) {
#pragma unroll
  for (int s = 32; s >= 1; s >>= 1) v += __shfl_xor(v, s, 64);
  __syncthreads();
  if ((t & 63) == 0) red[t >> 6] = v;
  __syncthreads();
  return red[0] + red[1] + red[2] + red[3];
}

__global__ __launch_bounds__(256) void finalize(
    const float* __restrict__ logits,   // [16384][3]
    const float* __restrict__ b2,       // [3]
    const int* __restrict__ seq_mask,   // [32][512]
    const int* __restrict__ ans,        // [32][8][512]
    const int* __restrict__ span,       // [32][512]
    const int* __restrict__ isbio,      // [32]
    float* __restrict__ out)            // [32]
{
  int b = blockIdx.x;
  int t = threadIdx.x;
  __shared__ float lp[512][3];
  __shared__ float red[4];
  __shared__ float seq_ll[9];
  __shared__ int preg;

  float b20 = b2[0], b21 = b2[1], b22 = b2[2];

  for (int l = t; l < 512; l += 256) {
    int gi = b * 512 + l;
    float x0 = logits[gi * 3 + 0] + b20;
    float x1 = logits[gi * 3 + 1] + b21;
    float x2 = logits[gi * 3 + 2] + b22;
    float mx = fmaxf(x0, fmaxf(x1, x2));
    float lse = mx + logf(expf(x0 - mx) + expf(x1 - mx) + expf(x2 - mx));
    float msk = (float)seq_mask[gi];
    lp[l][0] = (x0 - lse) * msk;
    lp[l][1] = (x1 - lse) * msk;
    lp[l][2] = (x2 - lse) * msk;
  }
  __syncthreads();

  // is_pregen = sum(ans * seq_mask) > 0
  float s = 0.f;
  for (int i = t; i < 8 * 512; i += 256) {
    int m = i >> 9, l = i & 511;
    s += (float)(ans[(b * 8 + m) * 512 + l] * seq_mask[b * 512 + l]);
  }
  s = blockReduceSum(s, red, t);
  if (t == 0) preg = (s > 0.f) ? 1 : 0;
  __syncthreads();
  int ip = preg;

  for (int m = 0; m < 9; ++m) {
    float sll = 0.f, sidx = 0.f;
    for (int l = t; l < 512; l += 256) {
      int idx;
      if (m < 8) idx = ans[(b * 8 + m) * 512 + l] * seq_mask[b * 512 + l];
      else       idx = span[b * 512 + l] * (1 - ip);
      sll  += lp[l][idx];
      sidx += (float)idx;
    }
    sll  = blockReduceSum(sll, red, t);
    sidx = blockReduceSum(sidx, red, t);
    if (t == 0) seq_ll[m] = (sidx > 0.f) ? sll : NEGV;
  }

  if (t == 0) {
    float mx = seq_ll[0];
#pragma unroll
    for (int m = 1; m < 9; ++m) mx = fmaxf(mx, seq_ll[m]);
    float sum = 0.f;
#pragma unroll
    for (int m = 0; m < 9; ++m) sum += expf(seq_ll[m] - mx);
    float lml = mx + logf(sum);
    out[b] = isbio[b] ? lml : NEGV;
  }
}

extern "C" void kernel_launch(void* const* d_in, const int* in_sizes, int n_in,
                              void* d_out, int out_size, void* d_ws, size_t ws_size,
                              hipStream_t stream) {
  const float* bert     = (const float*)d_in[0];
  const int*   seq_mask = (const int*)d_in[1];
  // d_in[2] wordpiece_mask: unused
  // d_in[3] answer_as_text_to_disjoint_bios: unused
  const int*   ans      = (const int*)d_in[4];
  const int*   span     = (const int*)d_in[5];
  const int*   isbio    = (const int*)d_in[6];
  const float* W1       = (const float*)d_in[7];
  const float* b1       = (const float*)d_in[8];
  const float* W2       = (const float*)d_in[9];
  const float* b2       = (const float*)d_in[10];
  float* out = (float*)d_out;

  char* ws = (char*)d_ws;
  float* logits          = (float*)ws;                                   // 192 KB
  unsigned short* Abf    = (unsigned short*)(ws + (1 << 20));            // 32 MB
  unsigned short* W1T    = (unsigned short*)(ws + (1 << 20) + (size_t)16384 * 1024 * 2); // 2 MB

  hipMemsetAsync(logits, 0, 16384 * 3 * sizeof(float), stream);
  cvt_a<<<2048, 256, 0, stream>>>(bert, Abf, 16384 * 1024 / 4);
  cvt_w1t<<<1024, 256, 0, stream>>>(W1, W1T);
  gemm_fused<<<1024, 256, 0, stream>>>(Abf, W1T, b1, W2, logits);
  finalize<<<32, 256, 0, stream>>>(logits, b2, seq_mask, ans, span, isbio, out);
}

// Round 2
// 126.941 us; speedup vs baseline: 1.1237x; 1.1237x over previous
//
#include <hip/hip_runtime.h>
#include <hip/hip_bf16.h>
#include <cstdint>

#define GLOBAL_AS __attribute__((address_space(1)))
#define LDS_AS    __attribute__((address_space(3)))

typedef short s8v  __attribute__((ext_vector_type(8)));
typedef float f4v  __attribute__((ext_vector_type(4)));
typedef unsigned short u8s __attribute__((ext_vector_type(8)));

#define NEGV (-1e7f)

__device__ __forceinline__ void gload_lds16(const void* g, void* l) {
  __builtin_amdgcn_global_load_lds((const GLOBAL_AS uint32_t*)g,
                                   (LDS_AS uint32_t*)l, 16, 0, 0);
}

__device__ __forceinline__ unsigned short f2bf(float f) {
  union { float f; uint32_t u; } v; v.f = f;
  uint32_t u = v.u;
  u += 0x7fffu + ((u >> 16) & 1u);
  return (unsigned short)(u >> 16);
}

// ---------------- convert bert_out (f32) -> bf16, same layout ----------------
__global__ __launch_bounds__(256) void cvt_a(const float* __restrict__ x,
                                             unsigned short* __restrict__ y,
                                             int n8) {
  int i = blockIdx.x * blockDim.x + threadIdx.x;
  int stride = gridDim.x * blockDim.x;
  for (; i < n8; i += stride) {
    float4 a = ((const float4*)x)[2 * i + 0];
    float4 b = ((const float4*)x)[2 * i + 1];
    u8s o;
    o[0] = f2bf(a.x); o[1] = f2bf(a.y); o[2] = f2bf(a.z); o[3] = f2bf(a.w);
    o[4] = f2bf(b.x); o[5] = f2bf(b.y); o[6] = f2bf(b.z); o[7] = f2bf(b.w);
    ((u8s*)y)[i] = o;
  }
}

// ------------- convert + transpose W1 (K x N f32) -> W1T (N x K bf16) -------------
__global__ __launch_bounds__(256) void cvt_w1t(const float* __restrict__ w1,
                                               unsigned short* __restrict__ w1t) {
  __shared__ float tile[32][33];
  int bx = blockIdx.x & 31;   // n-tile
  int by = blockIdx.x >> 5;   // k-tile
  int tx = threadIdx.x & 31;
  int ty = threadIdx.x >> 5;  // 0..7
#pragma unroll
  for (int j = 0; j < 4; ++j) {
    int kk = ty + j * 8;
    tile[kk][tx] = w1[(size_t)(by * 32 + kk) * 1024 + bx * 32 + tx];
  }
  __syncthreads();
#pragma unroll
  for (int j = 0; j < 4; ++j) {
    int nn = ty + j * 8;
    w1t[(size_t)(bx * 32 + nn) * 1024 + by * 32 + tx] = f2bf(tile[tx][nn]);
  }
}

// ---------------- fused GEMM: h = relu(A*W1 + b1); logits += h * W2 ----------------
// 128x128 tile, BK=64, 4 waves (2x2 of 64x64), mfma_f32_16x16x32_bf16.
// Double-buffered LDS + raw s_barrier + counted vmcnt(8) (T3/T4 minimum 2-phase):
// next tile's 8 global_load_lds per wave stay in flight across the barrier.
// LDS XOR-swizzle (rule 21): inverse-swizzled global source, linear gload_lds
// dest, swizzled ds_read_b128 — bank conflicts measured 0.
__global__ __launch_bounds__(256, 2) void gemm_fused(
    const unsigned short* __restrict__ Abf,
    const unsigned short* __restrict__ Bbf,
    const float* __restrict__ b1,
    const float* __restrict__ W2,     // [1024][3] f32
    float* __restrict__ logits)       // [16384][3] f32, pre-zeroed
{
  __shared__ __align__(16) char lds[65536];   // 2 buffers x (16KB A + 16KB B)

  // bijective XCD swizzle: 1024 wgs, 8 XCDs, 128 per XCD
  int bid = blockIdx.x;
  int wid = (bid & 7) * 128 + (bid >> 3);
  int mt = wid >> 3;   // 0..127
  int nt = wid & 7;    // 0..7

  int tid  = threadIdx.x;
  int lane = tid & 63;
  int wv   = tid >> 6;
  int wr   = wv >> 1;  // wave row (0..1)
  int wc   = wv & 1;   // wave col (0..1)

  // per-lane epilogue constants (column-indexed)
  float b1v[4];
  float w2v[4][3];
#pragma unroll
  for (int n = 0; n < 4; ++n) {
    int gc = nt * 128 + wc * 64 + n * 16 + (lane & 15);
    b1v[n] = b1[gc];
    w2v[n][0] = W2[gc * 3 + 0];
    w2v[n][1] = W2[gc * 3 + 1];
    w2v[n][2] = W2[gc * 3 + 2];
  }

  f4v acc[4][4];
#pragma unroll
  for (int m = 0; m < 4; ++m)
#pragma unroll
    for (int n = 0; n < 4; ++n)
      acc[m][n] = f4v{0.f, 0.f, 0.f, 0.f};

  const size_t arow0 = (size_t)mt * 128;
  const size_t brow0 = (size_t)nt * 128;

  // staging geometry (per wave: 4 chunks of 1 KB each for A and B -> 8 loads/wave)
  int srow_base = (wv * 4) * 8;
  int slane_row = lane >> 3;        // 0..7 within chunk
  int scb       = (lane & 7) * 16;  // byte col 0..112

  auto STAGE = [&](int k0, int buf) {
    char* As = lds + buf * 32768;
    char* Bs = As + 16384;
#pragma unroll
    for (int c = 0; c < 4; ++c) {
      int chunk = wv * 4 + c;
      int row = srow_base + c * 8 + slane_row;       // 0..127
      int src = scb ^ ((row & 7) << 4);              // inverse-swizzled source col
      gload_lds16(Abf + (arow0 + row) * 1024 + k0 + (src >> 1), As + chunk * 1024);
      gload_lds16(Bbf + (brow0 + row) * 1024 + k0 + (src >> 1), Bs + chunk * 1024);
    }
  };

  auto COMPUTE = [&](int buf) {
    const char* As = lds + buf * 32768;
    const char* Bs = As + 16384;
#pragma unroll
    for (int kh = 0; kh < 2; ++kh) {
      int kbyte = kh * 64 + ((lane >> 4) << 4);
      s8v av[4], bv[4];
#pragma unroll
      for (int m = 0; m < 4; ++m) {
        int ra = wr * 64 + m * 16 + (lane & 15);
        av[m] = *(const s8v*)(As + ra * 128 + (kbyte ^ ((ra & 7) << 4)));
        int rb = wc * 64 + m * 16 + (lane & 15);
        bv[m] = *(const s8v*)(Bs + rb * 128 + (kbyte ^ ((rb & 7) << 4)));
      }
      __builtin_amdgcn_s_setprio(1);
#pragma unroll
      for (int m = 0; m < 4; ++m)
#pragma unroll
        for (int n = 0; n < 4; ++n)
          acc[m][n] = __builtin_amdgcn_mfma_f32_16x16x32_bf16(av[m], bv[n], acc[m][n], 0, 0, 0);
      __builtin_amdgcn_s_setprio(0);
    }
  };

  STAGE(0, 0);
  for (int t = 0; t < 15; ++t) {
    STAGE((t + 1) * 64, (t + 1) & 1);                 // prefetch next tile (8 loads/wave)
    asm volatile("s_waitcnt vmcnt(8)" ::: "memory");  // tile t landed; next stays in flight
    __builtin_amdgcn_s_barrier();
    __builtin_amdgcn_sched_barrier(0);
    COMPUTE(t & 1);
    __builtin_amdgcn_sched_barrier(0);
    __builtin_amdgcn_s_barrier();                     // all reads done before overwrite
  }
  asm volatile("s_waitcnt vmcnt(0)" ::: "memory");
  __builtin_amdgcn_s_barrier();
  COMPUTE(1);

  // epilogue: h = relu(acc + b1), partial logits = h * W2, reduce over 16 lanes, atomicAdd
#pragma unroll
  for (int m = 0; m < 4; ++m) {
#pragma unroll
    for (int q = 0; q < 4; ++q) {
      float p0 = 0.f, p1 = 0.f, p2 = 0.f;
#pragma unroll
      for (int n = 0; n < 4; ++n) {
        float h = acc[m][n][q] + b1v[n];
        h = fmaxf(h, 0.f);
        p0 += h * w2v[n][0];
        p1 += h * w2v[n][1];
        p2 += h * w2v[n][2];
      }
#pragma unroll
      for (int s = 1; s < 16; s <<= 1) {
        p0 += __shfl_xor(p0, s, 64);
        p1 += __shfl_xor(p1, s, 64);
        p2 += __shfl_xor(p2, s, 64);
      }
      if ((lane & 15) == 0) {
        int grow = mt * 128 + wr * 64 + m * 16 + (lane >> 4) * 4 + q;
        atomicAdd(&logits[grow * 3 + 0], p0);
        atomicAdd(&logits[grow * 3 + 1], p1);
        atomicAdd(&logits[grow * 3 + 2], p2);
      }
    }
  }
}

// ---------------- finalize: log-softmax, gather, logsumexp ----------------
__device__ __forceinline__ float blockReduceSum(float v, float* red, int t) {
#pragma unroll
  for (int s = 32; s >= 1; s >>= 1) v += __shfl_xor(v, s, 64);
  __syncthreads();
  if ((t & 63) == 0) red[t >> 6] = v;
  __syncthreads();
  return red[0] + red[1] + red[2] + red[3];
}

__global__ __launch_bounds__(256) void finalize(
    const float* __restrict__ logits,   // [16384][3]
    const float* __restrict__ b2,       // [3]
    const int* __restrict__ seq_mask,   // [32][512]
    const int* __restrict__ ans,        // [32][8][512]
    const int* __restrict__ span,       // [32][512]
    const int* __restrict__ isbio,      // [32]
    float* __restrict__ out)            // [32]
{
  int b = blockIdx.x;
  int t = threadIdx.x;
  __shared__ float lp[512][3];
  __shared__ float red[4];
  __shared__ float seq_ll[9];
  __shared__ int preg;

  float b20 = b2[0], b21 = b2[1], b22 = b2[2];

  for (int l = t; l < 512; l += 256) {
    int gi = b * 512 + l;
    float x0 = logits[gi * 3 + 0] + b20;
    float x1 = logits[gi * 3 + 1] + b21;
    float x2 = logits[gi * 3 + 2] + b22;
    float mx = fmaxf(x0, fmaxf(x1, x2));
    float lse = mx + logf(expf(x0 - mx) + expf(x1 - mx) + expf(x2 - mx));
    float msk = (float)seq_mask[gi];
    lp[l][0] = (x0 - lse) * msk;
    lp[l][1] = (x1 - lse) * msk;
    lp[l][2] = (x2 - lse) * msk;
  }
  __syncthreads();

  // is_pregen = sum(ans * seq_mask) > 0
  float s = 0.f;
  for (int i = t; i < 8 * 512; i += 256) {
    int m = i >> 9, l = i & 511;
    s += (float)(ans[(b * 8 + m) * 512 + l] * seq_mask[b * 512 + l]);
  }
  s = blockReduceSum(s, red, t);
  if (t == 0) preg = (s > 0.f) ? 1 : 0;
  __syncthreads();
  int ip = preg;

  for (int m = 0; m < 9; ++m) {
    float sll = 0.f, sidx = 0.f;
    for (int l = t; l < 512; l += 256) {
      int idx;
      if (m < 8) idx = ans[(b * 8 + m) * 512 + l] * seq_mask[b * 512 + l];
      else       idx = span[b * 512 + l] * (1 - ip);
      sll  += lp[l][idx];
      sidx += (float)idx;
    }
    sll  = blockReduceSum(sll, red, t);
    sidx = blockReduceSum(sidx, red, t);
    if (t == 0) seq_ll[m] = (sidx > 0.f) ? sll : NEGV;
  }

  if (t == 0) {
    float mx = seq_ll[0];
#pragma unroll
    for (int m = 1; m < 9; ++m) mx = fmaxf(mx, seq_ll[m]);
    float sum = 0.f;
#pragma unroll
    for (int m = 0; m < 9; ++m) sum += expf(seq_ll[m] - mx);
    float lml = mx + logf(sum);
    out[b] = isbio[b] ? lml : NEGV;
  }
}

extern "C" void kernel_launch(void* const* d_in, const int* in_sizes, int n_in,
                              void* d_out, int out_size, void* d_ws, size_t ws_size,
                              hipStream_t stream) {
  const float* bert     = (const float*)d_in[0];
  const int*   seq_mask = (const int*)d_in[1];
  // d_in[2] wordpiece_mask: unused
  // d_in[3] answer_as_text_to_disjoint_bios: unused
  const int*   ans      = (const int*)d_in[4];
  const int*   span     = (const int*)d_in[5];
  const int*   isbio    = (const int*)d_in[6];
  const float* W1       = (const float*)d_in[7];
  const float* b1       = (const float*)d_in[8];
  const float* W2       = (const float*)d_in[9];
  const float* b2       = (const float*)d_in[10];
  float* out = (float*)d_out;

  char* ws = (char*)d_ws;
  float* logits          = (float*)ws;                                   // 192 KB
  unsigned short* Abf    = (unsigned short*)(ws + (1 << 20));            // 32 MB
  unsigned short* W1T    = (unsigned short*)(ws + (1 << 20) + (size_t)16384 * 1024 * 2); // 2 MB

  hipMemsetAsync(logits, 0, 16384 * 3 * sizeof(float), stream);
  cvt_a<<<2048, 256, 0, stream>>>(bert, Abf, 16384 * 1024 / 8);
  cvt_w1t<<<1024, 256, 0, stream>>>(W1, W1T);
  gemm_fused<<<1024, 256, 0, stream>>>(Abf, W1T, b1, W2, logits);
  finalize<<<32, 256, 0, stream>>>(logits, b2, seq_mask, ans, span, isbio, out);
}